// Round 10
// baseline (244.278 us; speedup 1.0000x reference)
//
#include <hip/hip_runtime.h>
#include <hip/hip_bf16.h>

#define BATCH    32768
#define HD       256
#define TM       32          // samples per block = two 16-sample tiles
#define ST       16
#define NTHREADS 512

#define SCL    2.8853900817779268f   // 2*log2(e): tanh(x) = 1 - 2/(exp2(SCL*x)+1)
#define SCLINV 0.3465735902799726f   // 1/SCL

typedef short  short8 __attribute__((ext_vector_type(8)));
typedef float  f32x16 __attribute__((ext_vector_type(16)));
typedef float  f32x2  __attribute__((ext_vector_type(2)));

// scalar f32 -> bf16 RNE (prepack only)
__device__ __forceinline__ unsigned short f2bf(float f) {
    unsigned u = __float_as_uint(f);
    return (unsigned short)((u + 0x7FFFu + ((u >> 16) & 1u)) >> 16);
}

// packed f32 pair -> bf16x2 (v_cvt_pk_bf16_f32)
__device__ __forceinline__ unsigned pk2(float a, float b) {
    __hip_bfloat162 h = __float22bfloat162_rn(make_float2(a, b));
    return *reinterpret_cast<unsigned*>(&h);
}

// ---- prepack W2^T (scaled by SCL) into bf16 MFMA A-fragment order ----
// A-frag for v_mfma_f32_32x32x16_bf16: lane l holds A[mt*32 + (l&31)][kstep*16 + (l>>5)*8 + i]
// where A = SCL * W2^T. chunk (mt, kstep) at ((mt*16 + kstep)*64 + lane)*8 + i
__global__ void prepack_w2t(const float* __restrict__ W2, unsigned short* __restrict__ wsA) {
    const int k = blockIdx.x;        // K row of W2
    const int j = threadIdx.x;       // output column j (row of W2^T)
    const unsigned short b = f2bf(SCL * W2[k * HD + j]);
    const int kstep = k >> 4, kl = k & 15, hi2 = kl >> 3, i = kl & 7;
    const int mt = j >> 5, jl = j & 31;
    wsA[(((mt * 16) + kstep) * 64 + (hi2 * 32 + jl)) * 8 + i] = b;
}

__global__ __launch_bounds__(NTHREADS, 4)
void cnf1d_rk4_mfma9(const float* __restrict__ z0,
                     const float* __restrict__ W1,
                     const float* __restrict__ b1,
                     const float* __restrict__ b2,
                     const float* __restrict__ W3,
                     const float* __restrict__ b3,
                     const unsigned short* __restrict__ wsA,
                     float* __restrict__ out)
{
    // staging per tile: 32 granules (k/8) x 32 cols (col = 2*sample + stream), 16B slots
    __shared__ __align__(16) short Ab[2][32][32][8];          // 32 KB
    __shared__ float w1zS[HD], w1tS[HD], b1S[HD], w0S[HD];    // 4 KB
    __shared__ float b2sc[HD], w3t[HD];                       // 2 KB
    __shared__ float2 kz[2][8][ST];                           // 2 KB   -> 40 KB total

    const int tid  = threadIdx.x;
    const int s0   = blockIdx.x * TM;
    const int lane = tid & 63;
    const int ln31 = lane & 31;
    const int hi   = lane >> 5;
    const int wid  = tid >> 6;        // wave 0..7: j-tile [wid*32, wid*32+32)
    const int sloc = tid & 15;        // sample within tile (stage/p4 role)
    const int fq   = tid >> 4;        // feature granule 0..31 (8 feats each)
    const int jb   = wid * 32 + hi * 4;
    const bool isT = (lane & 1) != 0; // odd D/B-col = tangent stream

    if (tid < HD) {
        const float w0 = W1[tid];
        w1zS[tid] = SCL * w0;
        w1tS[tid] = SCL * W1[HD + tid];
        b1S[tid]  = SCL * b1[tid];
        w0S[tid]  = w0;
        b2sc[tid] = SCL * b2[tid];
        w3t[tid]  = W3[tid];
    }

    // loop-invariant W2^T fragments in registers (64 VGPR)
    const short8* __restrict__ wsA8 = (const short8*)wsA;
    short8 w2f[16];
    #pragma unroll
    for (int kk = 0; kk < 16; ++kk)
        w2f[kk] = wsA8[(wid * 16 + kk) * 64 + lane];

    // RK4 state (per-thread, redundant across the 32 threads sharing a sloc)
    float zbA = z0[s0 + sloc];
    float zbB = z0[s0 + ST + sloc];
    float zcA = zbA, zcB = zbB;
    float skzA = 0.f, skdA = 0.f, daccA = 0.f;
    float skzB = 0.f, skdB = 0.f, daccB = 0.f;

    const float dt  = 0.25f;
    const float b3v = b3[0];
    uint4* __restrict__ Ab4 = (uint4*)Ab;
    const short8* __restrict__ Ab8 = (const short8*)Ab;
    const f32x2 one2 = {1.f, 1.f};
    const f32x2 m2   = {-2.f, -2.f};

    // ---- helpers ----
    auto stage = [&](int X, float zc, float tev) {
        const f32x2 zc2 = {zc, zc};
        const f32x2 te2 = {tev, tev};
        const int j0 = fq * 8;
        const float4 wzA = *(const float4*)&w1zS[j0];
        const float4 wzB = *(const float4*)&w1zS[j0 + 4];
        const float4 wtA = *(const float4*)&w1tS[j0];
        const float4 wtB = *(const float4*)&w1tS[j0 + 4];
        const float4 bbA = *(const float4*)&b1S[j0];
        const float4 bbB = *(const float4*)&b1S[j0 + 4];
        const float4 w0A = *(const float4*)&w0S[j0];
        const float4 w0B = *(const float4*)&w0S[j0 + 4];
        const f32x2 wz[4]  = {{wzA.x, wzA.y}, {wzA.z, wzA.w}, {wzB.x, wzB.y}, {wzB.z, wzB.w}};
        const f32x2 wt[4]  = {{wtA.x, wtA.y}, {wtA.z, wtA.w}, {wtB.x, wtB.y}, {wtB.z, wtB.w}};
        const f32x2 bb[4]  = {{bbA.x, bbA.y}, {bbA.z, bbA.w}, {bbB.x, bbB.y}, {bbB.z, bbB.w}};
        const f32x2 w0p[4] = {{w0A.x, w0A.y}, {w0A.z, w0A.w}, {w0B.x, w0B.y}, {w0B.z, w0B.w}};
        uint4 vU, vT;
        unsigned* pU = (unsigned*)&vU;
        unsigned* pT = (unsigned*)&vT;
        #pragma unroll
        for (int pp = 0; pp < 4; ++pp) {
            const f32x2 a = __builtin_elementwise_fma(zc2, wz[pp],
                              __builtin_elementwise_fma(te2, wt[pp], bb[pp]));
            f32x2 ev; ev.x = __builtin_amdgcn_exp2f(a.x);
                      ev.y = __builtin_amdgcn_exp2f(a.y);
            const f32x2 e1 = ev + one2;
            f32x2 rv; rv.x = __builtin_amdgcn_rcpf(e1.x);
                      rv.y = __builtin_amdgcn_rcpf(e1.y);
            const f32x2 h  = __builtin_elementwise_fma(m2, rv, one2);   // tanh pair
            const f32x2 t1 = __builtin_elementwise_fma(-h, h, one2);    // 1 - h^2
            const f32x2 th = t1 * w0p[pp];
            pU[pp] = pk2(h.x, h.y);
            pT[pp] = pk2(th.x, th.y);
        }
        const int base = (X * 32 + fq) * 32 + 2 * sloc;
        Ab4[base]     = vU;    // U col
        Ab4[base + 1] = vT;    // T col
    };

    auto mfma_tile = [&](int X) -> f32x16 {
        f32x16 acc;
        #pragma unroll
        for (int rq = 0; rq < 4; ++rq) {
            const float4 bq = *(const float4*)&b2sc[jb + rq * 8];
            acc[rq * 4 + 0] = isT ? 0.f : bq.x;
            acc[rq * 4 + 1] = isT ? 0.f : bq.y;
            acc[rq * 4 + 2] = isT ? 0.f : bq.z;
            acc[rq * 4 + 3] = isT ? 0.f : bq.w;
        }
        #pragma unroll
        for (int kk = 0; kk < 16; ++kk) {
            const short8 hB = Ab8[(X * 32 + kk * 2 + hi) * 32 + ln31];
            acc = __builtin_amdgcn_mfma_f32_32x32x16_bf16(w2f[kk], hB, acc, 0, 0, 0);
        }
        return acc;
    };

    auto epi = [&](int X, f32x16 acc) {
        float pdz = 0.f, pdd = 0.f;
        #pragma unroll
        for (int rq = 0; rq < 4; ++rq) {
            const float4 w3q = *(const float4*)&w3t[jb + rq * 8];
            #pragma unroll
            for (int rr = 0; rr < 4; ++rr) {
                const int r = rq * 4 + rr;
                const float tval = __shfl_xor(acc[r], 1);        // partner stream (DPP)
                const float ev   = __builtin_amdgcn_exp2f(acc[r]);
                const float r1   = __builtin_amdgcn_rcpf(ev + 1.f);
                const float h2   = fmaf(-2.f, r1, 1.f);          // tanh (valid on even lanes)
                const float th2  = fmaf(-h2 * h2, tval, tval);   // (1-h2^2)*SCL*tu
                const float w3c  = ((const float*)&w3q)[rr];
                pdz = fmaf(h2,  w3c, pdz);
                pdd = fmaf(th2, w3c, pdd);
            }
        }
        pdd *= SCLINV;
        pdz += __shfl_xor(pdz, 32);
        pdd += __shfl_xor(pdd, 32);
        if (hi == 0 && !(ln31 & 1)) kz[X][wid][ln31 >> 1] = make_float2(pdz, pdd);
    };

    auto p4 = [&](int X, int n, float& zb, float& zc, float& skz, float& skd, float& dacc) {
        float kzS = b3v, kdS = 0.f;
        #pragma unroll
        for (int w = 0; w < 8; ++w) {
            const float2 a = kz[X][w][sloc];
            kzS += a.x; kdS += a.y;
        }
        const int e = n & 3;
        const float cw = (e == 1 || e == 2) ? 2.f : 1.f;
        skz += cw * kzS;
        skd += cw * kdS;
        if (e < 3) {
            zc = fmaf((e == 2) ? dt : 0.5f * dt, kzS, zb);
        } else {
            zb   = fmaf(dt / 6.f, skz, zb);
            zc   = zb;
            dacc = fmaf(dt / 6.f, skd, dacc);
            skz = 0.f; skd = 0.f;
        }
    };

    auto te_of = [&](int n) -> float {
        const int e = n & 3;
        return (n >> 2) * dt + ((e == 0) ? 0.f : (e == 3) ? dt : 0.5f * dt);
    };

    __syncthreads();                 // params visible
    stage(0, zcA, te_of(0));         // prologue: tile A, eval 0
    __syncthreads();

    for (int it = 0; it < 16; ++it) {
        // ---- Rx: MFMA(A,it) || { p4(B,it-1), stage(B,it) } ----
        f32x16 accA = mfma_tile(0);
        if (it > 0) p4(1, it - 1, zbB, zcB, skzB, skdB, daccB);
        stage(1, zcB, te_of(it));
        __syncthreads();

        // ---- Ry: MFMA(B,it) || epi(A,it) -> kz[0] ----
        f32x16 accB = mfma_tile(1);
        epi(0, accA);
        __syncthreads();

        // ---- Rz: epi(B,it) -> kz[1] ; p4(A,it) ; stage(A,it+1) ----
        epi(1, accB);
        p4(0, it, zbA, zcA, skzA, skdA, daccA);
        if (it < 15) stage(0, zcA, te_of(it + 1));
        __syncthreads();
    }
    p4(1, 15, zbB, zcB, skzB, skdB, daccB);   // final tile-B update

    if (tid < TM) {
        const bool tB = tid >= ST;
        out[s0 + tid]         = tB ? zbB   : zbA;    // zf
        out[BATCH + s0 + tid] = tB ? daccB : daccA;  // div_int
    }
}

extern "C" void kernel_launch(void* const* d_in, const int* in_sizes, int n_in,
                              void* d_out, int out_size, void* d_ws, size_t ws_size,
                              hipStream_t stream) {
    const float* z0 = (const float*)d_in[0];
    const float* W1 = (const float*)d_in[1];
    const float* b1 = (const float*)d_in[2];
    const float* W2 = (const float*)d_in[3];
    const float* b2 = (const float*)d_in[4];
    const float* W3 = (const float*)d_in[5];
    const float* b3 = (const float*)d_in[6];
    float* out = (float*)d_out;
    unsigned short* wsA = (unsigned short*)d_ws;   // 128 KB bf16 A-frag SCL*W2^T

    hipLaunchKernelGGL(prepack_w2t, dim3(HD), dim3(HD), 0, stream, W2, wsA);
    hipLaunchKernelGGL(cnf1d_rk4_mfma9, dim3(BATCH / TM), dim3(NTHREADS), 0, stream,
                       z0, W1, b1, b2, W3, b3, wsA, out);
}

// Round 11
// 164.304 us; speedup vs baseline: 1.4867x; 1.4867x over previous
//
#include <hip/hip_runtime.h>
#include <hip/hip_bf16.h>

#define BATCH    32768
#define HD       256
#define TM       32
#define NTHREADS 512

#define SCL    2.8853900817779268f   // 2*log2(e): tanh(x) = 1 - 2/(exp2(SCL*x)+1)
#define SCLINV 0.3465735902799726f   // 1/SCL

typedef short  short8 __attribute__((ext_vector_type(8)));
typedef float  f32x16 __attribute__((ext_vector_type(16)));
typedef float  f32x2  __attribute__((ext_vector_type(2)));

// scalar f32 -> bf16 RNE (prepack only)
__device__ __forceinline__ unsigned short f2bf(float f) {
    unsigned u = __float_as_uint(f);
    return (unsigned short)((u + 0x7FFFu + ((u >> 16) & 1u)) >> 16);
}

// packed f32 pair -> bf16x2 (v_cvt_pk_bf16_f32)
__device__ __forceinline__ unsigned pk2(float a, float b) {
    __hip_bfloat162 h = __float22bfloat162_rn(make_float2(a, b));
    return *reinterpret_cast<unsigned*>(&h);
}

// ---- prepack W2^T (scaled by SCL) into bf16 MFMA A-fragment order ----
// A-frag for v_mfma_f32_32x32x16_bf16: lane l holds A[mt*32 + (l&31)][kstep*16 + (l>>5)*8 + i]
// where A = SCL * W2^T. chunk (mt, kstep) at ((mt*16 + kstep)*64 + lane)*8 + i
__global__ void prepack_w2t(const float* __restrict__ W2, unsigned short* __restrict__ wsA) {
    const int k = blockIdx.x;        // K row of W2
    const int j = threadIdx.x;       // output column j (row of W2^T)
    const unsigned short b = f2bf(SCL * W2[k * HD + j]);
    const int kstep = k >> 4, kl = k & 15, hi2 = kl >> 3, i = kl & 7;
    const int mt = j >> 5, jl = j & 31;
    wsA[(((mt * 16) + kstep) * 64 + (hi2 * 32 + jl)) * 8 + i] = b;
}

__global__ __launch_bounds__(NTHREADS, 4)
void cnf1d_rk4_mfma10(const float* __restrict__ z0,
                      const float* __restrict__ W1,
                      const float* __restrict__ b1,
                      const float* __restrict__ b2,
                      const float* __restrict__ W3,
                      const float* __restrict__ b3,
                      const unsigned short* __restrict__ wsA,
                      float* __restrict__ out)
{
    // B staging: [h1^T cols 0..31 ; th1^T cols 32..63], bf16, blocked:
    // 16B slot (kgranule g = k/8, row) at uint4 index g*64 + row
    __shared__ __align__(16) short Abuf[64 * 256];    // 32 KB
    __shared__ float w1zS[HD], w1tS[HD], b1S[HD], w0S[HD];   // SoA params, 4 KB
    __shared__ float b2sc[HD], w3t[HD];               // SCL*b2, W3   2 KB
    __shared__ float2 kz[8][TM];                      // per-wave (pdz,pdd) 2 KB
                                                      // total 40,960 B
    const int tid  = threadIdx.x;
    const int s0   = blockIdx.x * TM;
    const int lane = tid & 63;
    const int ln31 = lane & 31;
    const int hi   = lane >> 5;
    const int wid  = tid >> 6;        // wave id 0..7: owns j in [wid*32, wid*32+32)
    const int s    = tid & 31;        // owned sample
    const int fb   = tid >> 5;        // phase-1 feature block 0..15 (16 features)

    // --- anti-phase entry skew (scalar-only, no vector state live yet):
    // odd-phase blocks park ~8k cycles ≈ half an eval period so the two
    // co-resident blocks' MFMA/VALU windows interleave instead of lock-step.
    // Phase parity differs for co-resident pairs under both {b,b+1} and
    // {b,b+256} dispatch pairings.
    if ((blockIdx.x ^ (blockIdx.x >> 8)) & 1) {
        #pragma unroll
        for (int i = 0; i < 4; ++i) __builtin_amdgcn_s_sleep(31);
    }

    if (tid < HD) {
        const float w0 = W1[tid];
        w1zS[tid] = SCL * w0;
        w1tS[tid] = SCL * W1[HD + tid];
        b1S[tid]  = SCL * b1[tid];
        w0S[tid]  = w0;
        b2sc[tid] = SCL * b2[tid];
        w3t[tid]  = W3[tid];
    }

    // ---- loop-invariant: this wave's W2^T fragments, in registers (64 VGPR) ----
    const short8* __restrict__ wsA8 = (const short8*)wsA;
    short8 w2f[16];
    #pragma unroll
    for (int kk = 0; kk < 16; ++kk)
        w2f[kk] = wsA8[(wid * 16 + kk) * 64 + lane];

    float zbr = z0[s0 + s];
    float zcr = zbr, skzr = 0.f, skdr = 0.f, daccr = 0.f;
    __syncthreads();

    const float dt  = 0.25f;
    const float b3v = b3[0];
    uint4* __restrict__ Ab4 = (uint4*)Abuf;
    const short8* __restrict__ Ab8 = (const short8*)Abuf;
    const int jb = wid * 32 + hi * 4;
    const f32x2 one2 = {1.f, 1.f};
    const f32x2 m2   = {-2.f, -2.f};

    for (int it = 0; it < 16; ++it) {
        const int e    = it & 3;
        const int step = it >> 2;
        const float te = step * dt + ((e == 0) ? 0.f : ((e == 3) ? dt : 0.5f * dt));

        // ---- phase 1: h1/th1 (16 features/thread), packed-f32 pairs ----
        {
            const f32x2 zc2 = {zcr, zcr};
            const f32x2 te2 = {te, te};
            #pragma unroll
            for (int g2 = 0; g2 < 2; ++g2) {
                const int j0 = fb * 16 + g2 * 8;
                const float4 wzA = *(const float4*)&w1zS[j0];
                const float4 wzB = *(const float4*)&w1zS[j0 + 4];
                const float4 wtA = *(const float4*)&w1tS[j0];
                const float4 wtB = *(const float4*)&w1tS[j0 + 4];
                const float4 bbA = *(const float4*)&b1S[j0];
                const float4 bbB = *(const float4*)&b1S[j0 + 4];
                const float4 w0A = *(const float4*)&w0S[j0];
                const float4 w0B = *(const float4*)&w0S[j0 + 4];
                const f32x2 wz[4] = {{wzA.x, wzA.y}, {wzA.z, wzA.w}, {wzB.x, wzB.y}, {wzB.z, wzB.w}};
                const f32x2 wt[4] = {{wtA.x, wtA.y}, {wtA.z, wtA.w}, {wtB.x, wtB.y}, {wtB.z, wtB.w}};
                const f32x2 bb[4] = {{bbA.x, bbA.y}, {bbA.z, bbA.w}, {bbB.x, bbB.y}, {bbB.z, bbB.w}};
                const f32x2 w0p[4] = {{w0A.x, w0A.y}, {w0A.z, w0A.w}, {w0B.x, w0B.y}, {w0B.z, w0B.w}};
                f32x2 hh[4], th[4];
                #pragma unroll
                for (int pp = 0; pp < 4; ++pp) {
                    const f32x2 a = __builtin_elementwise_fma(zc2, wz[pp],
                                      __builtin_elementwise_fma(te2, wt[pp], bb[pp]));
                    f32x2 ev; ev.x = __builtin_amdgcn_exp2f(a.x);
                              ev.y = __builtin_amdgcn_exp2f(a.y);
                    const f32x2 e1 = ev + one2;                       // v_pk_add_f32
                    f32x2 rv; rv.x = __builtin_amdgcn_rcpf(e1.x);
                              rv.y = __builtin_amdgcn_rcpf(e1.y);
                    const f32x2 h = __builtin_elementwise_fma(m2, rv, one2);   // tanh pair
                    const f32x2 t1 = __builtin_elementwise_fma(-h, h, one2);   // 1 - h^2
                    hh[pp] = h;
                    th[pp] = t1 * w0p[pp];                            // v_pk_mul_f32
                }
                uint4 vU, vT;
                vU.x = pk2(hh[0].x, hh[0].y);  vU.y = pk2(hh[1].x, hh[1].y);
                vU.z = pk2(hh[2].x, hh[2].y);  vU.w = pk2(hh[3].x, hh[3].y);
                vT.x = pk2(th[0].x, th[0].y);  vT.y = pk2(th[1].x, th[1].y);
                vT.z = pk2(th[2].x, th[2].y);  vT.w = pk2(th[3].x, th[3].y);
                const int gr = j0 >> 3;
                Ab4[gr * 64 + s]      = vU;   // U col s
                Ab4[gr * 64 + 32 + s] = vT;   // T col 32+s
            }
        }
        __syncthreads();

        // ---- phase 2: acc = SCL*(W2^T[j-tile] @ [h1;th1]^T) + SCL*b2 ----
        f32x16 accU, accT;
        #pragma unroll
        for (int rq = 0; rq < 4; ++rq) {
            const float4 bq = *(const float4*)&b2sc[jb + rq * 8];
            accU[rq * 4 + 0] = bq.x;  accU[rq * 4 + 1] = bq.y;
            accU[rq * 4 + 2] = bq.z;  accU[rq * 4 + 3] = bq.w;
            accT[rq * 4 + 0] = 0.f;   accT[rq * 4 + 1] = 0.f;
            accT[rq * 4 + 2] = 0.f;   accT[rq * 4 + 3] = 0.f;
        }

        #pragma unroll
        for (int kk = 0; kk < 16; ++kk) {
            const short8 hU = Ab8[(kk * 2 + hi) * 64 + ln31];
            const short8 hT = Ab8[(kk * 2 + hi) * 64 + 32 + ln31];
            accU = __builtin_amdgcn_mfma_f32_32x32x16_bf16(w2f[kk], hU, accU, 0, 0, 0);
            accT = __builtin_amdgcn_mfma_f32_32x32x16_bf16(w2f[kk], hT, accT, 0, 0, 0);
        }

        // ---- phase 3: epilogue, packed pairs; j-reduction in-lane (lane = sample) ----
        f32x2 pz2 = {0.f, 0.f}, pd2 = {0.f, 0.f};
        #pragma unroll
        for (int rq = 0; rq < 4; ++rq) {
            const float4 w3q = *(const float4*)&w3t[jb + rq * 8];
            const f32x2 w3p[2] = {{w3q.x, w3q.y}, {w3q.z, w3q.w}};
            #pragma unroll
            for (int pr = 0; pr < 2; ++pr) {
                const int r = rq * 4 + pr * 2;
                const f32x2 u2 = {accU[r], accU[r + 1]};              // SCL*(u+b2)
                const f32x2 t2 = {accT[r], accT[r + 1]};              // SCL*tu
                f32x2 ev; ev.x = __builtin_amdgcn_exp2f(u2.x);
                          ev.y = __builtin_amdgcn_exp2f(u2.y);
                const f32x2 e1 = ev + one2;
                f32x2 rv; rv.x = __builtin_amdgcn_rcpf(e1.x);
                          rv.y = __builtin_amdgcn_rcpf(e1.y);
                const f32x2 h2 = __builtin_elementwise_fma(m2, rv, one2);
                const f32x2 hq = h2 * h2;
                const f32x2 th2 = __builtin_elementwise_fma(-hq, t2, t2);  // (1-h2^2)*SCL*tu
                pz2 = __builtin_elementwise_fma(h2,  w3p[pr], pz2);
                pd2 = __builtin_elementwise_fma(th2, w3p[pr], pd2);
            }
        }
        float pdz = pz2.x + pz2.y;
        float pdd = (pd2.x + pd2.y) * SCLINV;        // undo tangent scale once
        pdz += __shfl_xor(pdz, 32);                  // combine hi halves (j += 4 rows)
        pdd += __shfl_xor(pdd, 32);
        if (hi == 0) kz[wid][ln31] = make_float2(pdz, pdd);
        __syncthreads();

        // ---- phase 4: RK4 update (registers, redundant across threads of a sample) ----
        {
            float k_z = b3v, k_d = 0.f;
            #pragma unroll
            for (int w = 0; w < 8; ++w) {
                const float2 a = kz[w][s];
                k_z += a.x; k_d += a.y;
            }
            const float cw = (e == 1 || e == 2) ? 2.f : 1.f;
            skzr += cw * k_z;
            skdr += cw * k_d;
            if (e < 3) {
                zcr = fmaf((e == 2) ? dt : 0.5f * dt, k_z, zbr);
            } else {
                zbr   = fmaf(dt / 6.f, skzr, zbr);
                zcr   = zbr;
                daccr = fmaf(dt / 6.f, skdr, daccr);
                skzr = 0.f; skdr = 0.f;
            }
        }
    }

    if (tid < TM) {
        out[s0 + tid]         = zbr;     // zf
        out[BATCH + s0 + tid] = daccr;   // div_int
    }
}

extern "C" void kernel_launch(void* const* d_in, const int* in_sizes, int n_in,
                              void* d_out, int out_size, void* d_ws, size_t ws_size,
                              hipStream_t stream) {
    const float* z0 = (const float*)d_in[0];
    const float* W1 = (const float*)d_in[1];
    const float* b1 = (const float*)d_in[2];
    const float* W2 = (const float*)d_in[3];
    const float* b2 = (const float*)d_in[4];
    const float* W3 = (const float*)d_in[5];
    const float* b3 = (const float*)d_in[6];
    float* out = (float*)d_out;
    unsigned short* wsA = (unsigned short*)d_ws;   // 128 KB bf16 A-frag SCL*W2^T

    hipLaunchKernelGGL(prepack_w2t, dim3(HD), dim3(HD), 0, stream, W2, wsA);
    hipLaunchKernelGGL(cnf1d_rk4_mfma10, dim3(BATCH / TM), dim3(NTHREADS), 0, stream,
                       z0, W1, b1, b2, W3, b3, wsA, out);
}